// Round 7
// baseline (89997.577 us; speedup 1.0000x reference)
//
#include <hip/hip_runtime.h>
#include <hip/hip_bf16.h>

// 2-layer GRU (torch gate order r,z,n) + residual, B=16 T=4096 IN=H=512.
//
// Round-7 = round-6 minus the crash suspect: NO untracked asm loads. The x
// prefetch is now a tracked C++ vector load issued at the top of phase A,
// before the ring poll; the poll's vmcnt(0) drains it (HBM latency overlaps
// the ring round-trip). No asm-written registers live across barriers.
//
// Architecture (unchanged from r5/r6):
//  - 16 WGs/layer x 384 thr (6 waves). WG owns 32 units. Wave = (side, gate),
//    2 N-tiles of stationary weights in VGPRs (128/thread). bounds(384,1).
//  - h/y published as tagged u32 (bf16<<16 | t+1) to L3 rings (sc0 sc1).
//    Tag rides with data -> no flags/fences; one L3 RT steady state. Stale
//    tags across graph replays match only for identical t => identical
//    deterministic data: benign. l2prog memset each launch.
//  - LDS staging rows padded to 528 u16: ds_read_b128 A-fragments spread
//    uniformly over all 32 banks.
//  - ONE kernel-level shared block used by both layer branches.

namespace {

constexpr int SEQ   = 4096;
constexpr int HD    = 512;
constexpr int NSLOT = 64;            // ring depth (steps)
constexpr int NWGL  = 16;            // WGs per layer
constexpr int SLICE = 32;            // units per WG
constexpr int BLK   = 384;           // 6 waves
constexpr int SLOTU = 16 * HD;       // 8192 u32 per ring slot
constexpr int ROWS  = 528;           // LDS row pitch in u16 (512 + 16 pad)

typedef short    bf16x8 __attribute__((ext_vector_type(8)));
typedef float    f32x4  __attribute__((ext_vector_type(4)));
typedef unsigned u32x4  __attribute__((ext_vector_type(4)));
typedef short    s16x4  __attribute__((ext_vector_type(4)));

__device__ __forceinline__ unsigned short f2bf(float f) {
  unsigned u = __float_as_uint(f);
  return (unsigned short)((u + 0x7fffu + ((u >> 16) & 1u)) >> 16);  // RNE
}
__device__ __forceinline__ float bf2f(unsigned short s) {
  return __uint_as_float(((unsigned)s) << 16);
}
__device__ __forceinline__ unsigned pack2(float lo, float hi) {
  return (unsigned)f2bf(lo) | ((unsigned)f2bf(hi) << 16);
}
__device__ __forceinline__ float sigm(float v) { return 1.f / (1.f + __expf(-v)); }
__device__ __forceinline__ float tanh_(float v) { return 1.f - 2.f / (1.f + __expf(2.f * v)); }

// ---- sc0 sc1 (device-coherent via L3) access helpers ----
__device__ __forceinline__ void ld_u32_nw(unsigned* d, const unsigned* p) {
  asm volatile("global_load_dword %0, %1, off sc0 sc1" : "=v"(*d) : "v"(p) : "memory");
}
__device__ __forceinline__ void ld_u32x4_nw(u32x4* d, const unsigned* p) {
  asm volatile("global_load_dwordx4 %0, %1, off sc0 sc1" : "=v"(*d) : "v"(p) : "memory");
}
__device__ __forceinline__ void st_u32_sc(unsigned* p, unsigned v) {
  asm volatile("global_store_dword %0, %1, off sc0 sc1" :: "v"(p), "v"(v) : "memory");
}
__device__ __forceinline__ void st_u32x4_sc(unsigned* p, u32x4 v) {
  asm volatile("global_store_dwordx4 %0, %1, off sc0 sc1" :: "v"(p), "v"(v) : "memory");
}
__device__ __forceinline__ void vmwait0() {
  asm volatile("s_waitcnt vmcnt(0)" ::: "memory");
  __builtin_amdgcn_sched_barrier(0);   // rule #18
}

#define MFMA16(a, b, c) __builtin_amdgcn_mfma_f32_16x16x32_bf16((a), (b), (c), 0, 0, 0)

// Optimistic chunk load: 8 dwordx4 granules (+8 more if TWO); ALL words
// tag-verified. Sentinel-poll fallback (1 word per granule) on staleness.
template <bool TWO>
__device__ __forceinline__ void poll_chunks(const unsigned* p0, unsigned tg0,
                                            const unsigned* p1, unsigned tg1,
                                            u32x4 (&v0)[8], u32x4 (&v1)[8]) {
  for (;;) {
    #pragma unroll
    for (int g = 0; g < 8; ++g) ld_u32x4_nw(&v0[g], p0 + g * 4);
    if (TWO) {
      #pragma unroll
      for (int g = 0; g < 8; ++g) ld_u32x4_nw(&v1[g], p1 + g * 4);
    }
    vmwait0();
    unsigned bad = 0;
    #pragma unroll
    for (int g = 0; g < 8; ++g)
      #pragma unroll
      for (int e = 0; e < 4; ++e) bad |= v0[g][e] ^ tg0;
    if (TWO) {
      #pragma unroll
      for (int g = 0; g < 8; ++g)
        #pragma unroll
        for (int e = 0; e < 4; ++e) bad |= v1[g][e] ^ tg1;
    }
    if (!(bad & 0xffffu)) return;
    // sentinel spin until fresh, then re-load full granules
    for (;;) {
      __builtin_amdgcn_s_sleep(1);
      unsigned sv[16];
      #pragma unroll
      for (int g = 0; g < 8; ++g) ld_u32_nw(&sv[g], p0 + g * 4 + 3);
      if (TWO) {
        #pragma unroll
        for (int g = 0; g < 8; ++g) ld_u32_nw(&sv[8 + g], p1 + g * 4 + 3);
      }
      vmwait0();
      unsigned bd = 0;
      #pragma unroll
      for (int g = 0; g < 8; ++g) bd |= sv[g] ^ tg0;
      if (TWO) {
        #pragma unroll
        for (int g = 0; g < 8; ++g) bd |= sv[8 + g] ^ tg1;
      }
      if (!(bd & 0xffffu)) break;
    }
  }
}

// Extract hi16 payloads from 8 tagged granules -> 4x b128 LDS writes (padded rows)
__device__ __forceinline__ void stage_lds(const u32x4 (&v)[8], short* base, int b, int kc) {
  char* rowp = (char*)(base + b * ROWS + kc * 32);
  #pragma unroll
  for (int blk = 0; blk < 4; ++blk) {
    const int bb = blk ^ (kc & 3);   // spread writes across bank groups
    const u32x4 a = v[bb * 2], d = v[bb * 2 + 1];
    u32x4 p;
    p[0] = (a[0] >> 16) | (a[1] & 0xffff0000u);
    p[1] = (a[2] >> 16) | (a[3] & 0xffff0000u);
    p[2] = (d[0] >> 16) | (d[1] & 0xffff0000u);
    p[3] = (d[2] >> 16) | (d[3] & 0xffff0000u);
    *(u32x4*)(rowp + bb * 16) = p;
  }
}

// Convert 32 f32 (x) -> bf16, same padded layout
__device__ __forceinline__ void stage_x(const f32x4 (&xl)[8], short* base, int b, int kc) {
  char* rowp = (char*)(base + b * ROWS + kc * 32);
  #pragma unroll
  for (int blk = 0; blk < 4; ++blk) {
    const int bb = blk ^ (kc & 3);
    const f32x4 a = xl[bb * 2], d = xl[bb * 2 + 1];
    u32x4 p;
    p[0] = pack2(a[0], a[1]);
    p[1] = pack2(a[2], a[3]);
    p[2] = pack2(d[0], d[1]);
    p[3] = pack2(d[2], d[3]);
    *(u32x4*)(rowp + bb * 16) = p;
  }
}

template <int LAYER>
__device__ void layer_fn(const float* __restrict__ x,
                         const float* __restrict__ Wih, const float* __restrict__ Whh,
                         const float* __restrict__ bih, const float* __restrict__ bhh,
                         float* __restrict__ out,
                         unsigned* l2prog, unsigned* yring, unsigned* h2ring,
                         int s, char* smem) {
  // shared carve-up (single 80640 B block, offsets all 16B-aligned)
  short* hstage = (short*)smem;                  // [2][16][ROWS] bf16   33792 B
  short* astage = (short*)(smem + 33792);        // [2][16][ROWS]        33792 B
  float* gb     = (float*)(smem + 67584);        // [12][16][16] f32     12288 B
  float* biasL  = (float*)(smem + 79872);        // [6][32] f32            768 B

  const int tid = threadIdx.x, w = tid >> 6, lane = tid & 63;
  const int c = lane & 15, q = lane >> 4;
  const int b = tid >> 4, kc = tid & 15;    // staging chunk coords (tid<256)

  unsigned* ownring = LAYER ? h2ring : yring;

  if (tid < 96) {
    const int g = tid >> 5, u = tid & 31;
    biasL[tid]      = bih[g * HD + s * SLICE + u];
    biasL[96 + tid] = bhh[g * HD + s * SLICE + u];
  }

  // stationary weights: wave -> (side, gate), 2 N-tiles of 16 units
  const int side = (w >= 3) ? 1 : 0, gate = side ? (w - 3) : w;
  const float* Wm = side ? Whh : Wih;
  bf16x8 wf0[16], wf1[16];
  {
    const float* p0 = Wm + ((size_t)gate * HD + s * SLICE + c) * HD + q * 8;
    const float* p1 = p0 + 16 * HD;
    #pragma unroll
    for (int kk = 0; kk < 16; ++kk) {
      bf16x8 f0, f1;
      #pragma unroll
      for (int i = 0; i < 8; ++i) {
        f0[i] = (short)f2bf(p0[kk * 32 + i]);
        f1[i] = (short)f2bf(p1[kk * 32 + i]);
      }
      wf0[kk] = f0;
      wf1[kk] = f1;
    }
  }

  f32x4 hreg = {0.f, 0.f, 0.f, 0.f};  // tid<128: own 4 units of h, fp32

  // pre-loop: stage x_0 into astage buf 0 (tracked loads; B1 of t=0 publishes)
  if (LAYER == 0 && tid < 256) {
    f32x4 xl[8];
    const float* px = x + (size_t)b * SEQ * HD + kc * 32;
    #pragma unroll
    for (int g2 = 0; g2 < 8; ++g2) xl[g2] = *(const f32x4*)(px + g2 * 4);
    stage_x(xl, astage, b, kc);
  }

  for (int t = 0; t < SEQ; ++t) {
    const int buf = t & 1;
    const int slot = t & (NSLOT - 1);

    // ---------- phase A: poll + stage ----------
    if (tid < 256) {
      u32x4 v0[8], v1[8];
      if (LAYER == 0) {
        // tracked x(t+1) loads issued BEFORE the poll; the poll's vmcnt(0)
        // drains them -> HBM latency overlaps the ring round-trip.
        f32x4 xl[8];
        if (t + 1 < SEQ) {
          const float* px = x + ((size_t)b * SEQ + (t + 1)) * HD + kc * 32;
          #pragma unroll
          for (int g2 = 0; g2 < 8; ++g2) xl[g2] = *(const f32x4*)(px + g2 * 4);
        }
        if (t > 0) {
          const unsigned* ph =
              yring + (size_t)((t - 1) & (NSLOT - 1)) * SLOTU + b * HD + kc * 32;
          poll_chunks<false>(ph, (unsigned)t, nullptr, 0u, v0, v1);
          stage_lds(v0, hstage + buf * (16 * ROWS), b, kc);
        }
        if (t + 1 < SEQ) stage_x(xl, astage + ((t + 1) & 1) * (16 * ROWS), b, kc);
      } else {
        const unsigned* py = yring + (size_t)slot * SLOTU + b * HD + kc * 32;
        if (t > 0) {
          const unsigned* ph =
              h2ring + (size_t)((t - 1) & (NSLOT - 1)) * SLOTU + b * HD + kc * 32;
          poll_chunks<true>(ph, (unsigned)t, py, (unsigned)(t + 1), v0, v1);
          stage_lds(v0, hstage + buf * (16 * ROWS), b, kc);
          stage_lds(v1, astage + buf * (16 * ROWS), b, kc);
        } else {
          poll_chunks<false>(py, 1u, nullptr, 0u, v0, v1);
          stage_lds(v0, astage, b, kc);
        }
      }
    } else if (tid == BLK - 1 && LAYER == 0 && t >= 32 && (t & 31) == 0) {
      // back-pressure: before writing y slots [t, t+32) ensure layer-2 staged
      // up to t-32 (slot reuse distance 64). Rarely blocks.
      const unsigned need = (unsigned)(t - 31);
      for (;;) {
        u32x4 pv[4];
        #pragma unroll
        for (int i = 0; i < 4; ++i) ld_u32x4_nw(&pv[i], l2prog + i * 4);
        vmwait0();
        unsigned m = 0xffffffffu;
        #pragma unroll
        for (int i = 0; i < 4; ++i)
          #pragma unroll
          for (int j = 0; j < 4; ++j) m = pv[i][j] < m ? pv[i][j] : m;
        if (m >= need) break;
        __builtin_amdgcn_s_sleep(16);
      }
    }
    __syncthreads();  // B1: stages ready

    if (LAYER == 1 && tid == BLK - 1) st_u32_sc(&l2prog[s], (unsigned)(t + 1));

    // ---------- matvec: wave computes its (side,gate) x 2 tiles ----------
    f32x4 a0 = {0.f,0.f,0.f,0.f}, a1 = {0.f,0.f,0.f,0.f};
    f32x4 a2 = {0.f,0.f,0.f,0.f}, a3 = {0.f,0.f,0.f,0.f};
    {
      const short* ap = (side ? hstage : astage) + buf * (16 * ROWS) + c * ROWS + q * 8;
      if (side == 0 || t > 0) {
        #pragma unroll
        for (int kk = 0; kk < 16; ++kk) {
          bf16x8 a = *(const bf16x8*)(ap + kk * 32);
          if (kk & 1) { a1 = MFMA16(a, wf0[kk], a1); a3 = MFMA16(a, wf1[kk], a3); }
          else        { a0 = MFMA16(a, wf0[kk], a0); a2 = MFMA16(a, wf1[kk], a2); }
        }
      }
      const f32x4 t0 = a0 + a1, t1 = a2 + a3;
      float* g0 = gb + ((side * 3 + gate) * 2 + 0) * 256;
      float* g1 = gb + ((side * 3 + gate) * 2 + 1) * 256;
      #pragma unroll
      for (int j = 0; j < 4; ++j) {
        g0[(q * 4 + j) * 16 + c] = t0[j];
        g1[(q * 4 + j) * 16 + c] = t1[j];
      }
    }
    __syncthreads();  // B2: gate pre-acts ready

    // ---------- epilogue: 128 threads x 4 units ----------
    if (tid < 128) {
      const int eb = tid >> 3, ug = (tid & 7) * 4, tile = ug >> 4, n0 = ug & 15;
      const float* gB = gb + tile * 256 + eb * 16 + n0;
      const f32x4 xr_ = *(const f32x4*)(gB + 0);
      const f32x4 xz_ = *(const f32x4*)(gB + 512);
      const f32x4 xn_ = *(const f32x4*)(gB + 1024);
      const f32x4 hr_ = *(const f32x4*)(gB + 1536);
      const f32x4 hz_ = *(const f32x4*)(gB + 2048);
      const f32x4 hn_ = *(const f32x4*)(gB + 2560);
      const f32x4 bIr = *(const f32x4*)(biasL + ug);
      const f32x4 bIz = *(const f32x4*)(biasL + 32 + ug);
      const f32x4 bIn = *(const f32x4*)(biasL + 64 + ug);
      const f32x4 bHr = *(const f32x4*)(biasL + 96 + ug);
      const f32x4 bHz = *(const f32x4*)(biasL + 128 + ug);
      const f32x4 bHn = *(const f32x4*)(biasL + 160 + ug);
      u32x4 pk;
      #pragma unroll
      for (int jj = 0; jj < 4; ++jj) {
        const float r = sigm(xr_[jj] + hr_[jj] + bIr[jj] + bHr[jj]);
        const float z = sigm(xz_[jj] + hz_[jj] + bIz[jj] + bHz[jj]);
        const float nn = tanh_(xn_[jj] + bIn[jj] + r * (hn_[jj] + bHn[jj]));
        const float hv = (1.f - z) * nn + z * hreg[jj];
        hreg[jj] = hv;
        pk[jj] = ((unsigned)f2bf(hv) << 16) | (unsigned)(t + 1);
      }
      st_u32x4_sc(ownring + (size_t)slot * SLOTU + eb * HD + s * SLICE + ug, pk);
      if (LAYER == 1) {
        const s16x4 yv =
            *(const s16x4*)(astage + buf * (16 * ROWS) + eb * ROWS + s * SLICE + ug);
        f32x4 o;
        #pragma unroll
        for (int jj = 0; jj < 4; ++jj) o[jj] = hreg[jj] + bf2f((unsigned short)yv[jj]);
        *(f32x4*)(out + ((size_t)eb * SEQ + t) * HD + s * SLICE + ug) = o;
      }
    }
    // no 3rd barrier needed: phase A(t+1) writes the other stage buffers; gb
    // rewrite happens after B1(t+1), which epilogue threads must reach first.
  }
}

__global__ __launch_bounds__(BLK, 1) void gru2_k(
    const float* __restrict__ x,
    const float* __restrict__ Wih1, const float* __restrict__ Whh1,
    const float* __restrict__ bih1, const float* __restrict__ bhh1,
    const float* __restrict__ Wih2, const float* __restrict__ Whh2,
    const float* __restrict__ bih2, const float* __restrict__ bhh2,
    float* __restrict__ out,
    unsigned* l2prog, unsigned* yring, unsigned* h2ring) {
  __shared__ alignas(16) char smem[80640];   // single block, both branches
  const int bx = blockIdx.x;
  if (bx < NWGL)
    layer_fn<0>(x, Wih1, Whh1, bih1, bhh1, out, l2prog, yring, h2ring, bx, smem);
  else
    layer_fn<1>(x, Wih2, Whh2, bih2, bhh2, out, l2prog, yring, h2ring, bx - NWGL, smem);
}

}  // namespace

extern "C" void kernel_launch(void* const* d_in, const int* in_sizes, int n_in,
                              void* d_out, int out_size, void* d_ws, size_t ws_size,
                              hipStream_t stream) {
  const float* x    = (const float*)d_in[0];
  const float* Wih1 = (const float*)d_in[1];
  const float* Whh1 = (const float*)d_in[2];
  const float* bih1 = (const float*)d_in[3];
  const float* bhh1 = (const float*)d_in[4];
  const float* Wih2 = (const float*)d_in[5];
  const float* Whh2 = (const float*)d_in[6];
  const float* bih2 = (const float*)d_in[7];
  const float* bhh2 = (const float*)d_in[8];

  unsigned* l2prog = (unsigned*)d_ws;                                   // 16 u32
  unsigned* yring  = (unsigned*)((char*)d_ws + 4096);                   // 2 MB
  unsigned* h2ring = yring + (size_t)NSLOT * SLOTU;                     // 2 MB

  // progress words must be zero each launch; rings are stale-accept-safe.
  hipMemsetAsync(d_ws, 0, 256, stream);

  gru2_k<<<dim3(2 * NWGL), dim3(BLK), 0, stream>>>(
      x, Wih1, Whh1, bih1, bhh1, Wih2, Whh2, bih2, bhh2,
      (float*)d_out, l2prog, yring, h2ring);
}

// Round 8
// 48049.527 us; speedup vs baseline: 1.8730x; 1.8730x over previous
//
#include <hip/hip_runtime.h>
#include <hip/hip_bf16.h>

// 2-layer GRU (torch gate order r,z,n) + residual, B=16 T=4096 IN=H=512.
//
// Round-8: minimize the synchronizing set.
//  - 4 recurrence WGs per layer, 256 thr (4 waves = 1 wave/SIMD -> 512-reg
//    budget). Each holds 384 rows of W_hh in VGPRs (384/lane) and owns 128
//    hidden units. Per-step exchange: 4 producers x 8KB tagged u32
//    (bf16<<16|t+1) through L3 (sc0 sc1), direct re-poll (no sentinel).
//  - 8 helper WGs per layer compute xg = in @ W_ih^T + b_ih (192 rows each,
//    weights in VGPRs) into 32-deep fp32 rings; tags (zeroed each launch)
//    published after drain+barrier.
//  - Rec WGs PREFETCH xg(t+1) and y(t+1) during step t -> steady-state
//    critical path is only the own-layer h exchange + matvec + epilogue.
//  - Layer-2 lags layer-1 by a constant pipeline offset; back-pressure
//    (ring reuse) polled once per 8 steps with generous slack.

namespace {

constexpr int SEQ   = 4096;
constexpr int HD    = 512;
constexpr int NSLOT = 32;          // ring depth (steps)
constexpr int XROW  = 3 * HD;      // 1536 gate rows
constexpr int ROWS  = 528;         // LDS row pitch (u16)
constexpr int SLOTU = 16 * HD;     // u32 per h slot

typedef short    bf16x8 __attribute__((ext_vector_type(8)));
typedef float    f32x4  __attribute__((ext_vector_type(4)));
typedef unsigned u32x4  __attribute__((ext_vector_type(4)));

__device__ __forceinline__ unsigned short f2bf(float f) {
  unsigned u = __float_as_uint(f);
  return (unsigned short)((u + 0x7fffu + ((u >> 16) & 1u)) >> 16);  // RNE
}
__device__ __forceinline__ float bf2f(unsigned short s) {
  return __uint_as_float(((unsigned)s) << 16);
}
__device__ __forceinline__ unsigned pack2(float lo, float hi) {
  return (unsigned)f2bf(lo) | ((unsigned)f2bf(hi) << 16);
}
__device__ __forceinline__ float sigm(float v) { return 1.f / (1.f + __expf(-v)); }
__device__ __forceinline__ float tanh_(float v) { return 1.f - 2.f / (1.f + __expf(2.f * v)); }

__device__ __forceinline__ void ld_u32x4_nw(u32x4* d, const unsigned* p) {
  asm volatile("global_load_dwordx4 %0, %1, off sc0 sc1" : "=v"(*d) : "v"(p) : "memory");
}
__device__ __forceinline__ void ld_f32x4_sc(f32x4* d, const float* p) {
  asm volatile("global_load_dwordx4 %0, %1, off sc0 sc1" : "=v"(*d) : "v"(p) : "memory");
}
__device__ __forceinline__ void st_u32_sc(unsigned* p, unsigned v) {
  asm volatile("global_store_dword %0, %1, off sc0 sc1" :: "v"(p), "v"(v) : "memory");
}
__device__ __forceinline__ void st_f32_sc(float* p, float v) {
  asm volatile("global_store_dword %0, %1, off sc0 sc1" :: "v"(p), "v"(v) : "memory");
}
__device__ __forceinline__ void st_u32x4_sc(unsigned* p, u32x4 v) {
  asm volatile("global_store_dwordx4 %0, %1, off sc0 sc1" :: "v"(p), "v"(v) : "memory");
}
__device__ __forceinline__ void vmwait0() {
  asm volatile("s_waitcnt vmcnt(0)" ::: "memory");
  __builtin_amdgcn_sched_barrier(0);   // rule #18
}

#define MFMA16(a, b, c) __builtin_amdgcn_mfma_f32_16x16x32_bf16((a), (b), (c), 0, 0, 0)

// hi16 extraction of 8 tagged granules -> 4x b128 LDS writes (padded rows)
__device__ __forceinline__ void stage_lds(const u32x4 (&v)[8], short* base, int b, int kc) {
  char* rowp = (char*)(base + b * ROWS + kc * 32);
  #pragma unroll
  for (int blk = 0; blk < 4; ++blk) {
    const int bb = blk ^ (kc & 3);
    const u32x4 a = v[bb * 2], d = v[bb * 2 + 1];
    u32x4 p;
    p[0] = (a[0] >> 16) | (a[1] & 0xffff0000u);
    p[1] = (a[2] >> 16) | (a[3] & 0xffff0000u);
    p[2] = (d[0] >> 16) | (d[1] & 0xffff0000u);
    p[3] = (d[2] >> 16) | (d[3] & 0xffff0000u);
    *(u32x4*)(rowp + bb * 16) = p;
  }
}

__device__ __forceinline__ void stage_x(const f32x4 (&xl)[8], short* base, int b, int kc) {
  char* rowp = (char*)(base + b * ROWS + kc * 32);
  #pragma unroll
  for (int blk = 0; blk < 4; ++blk) {
    const int bb = blk ^ (kc & 3);
    const f32x4 a = xl[bb * 2], d = xl[bb * 2 + 1];
    u32x4 p;
    p[0] = pack2(a[0], a[1]);
    p[1] = pack2(a[2], a[3]);
    p[2] = pack2(d[0], d[1]);
    p[3] = pack2(d[2], d[3]);
    *(u32x4*)(rowp + bb * 16) = p;
  }
}

// ---------------- recurrence WG: 256 thr, owns 128 units ----------------
template <int LAYER>
__device__ void rec_fn(const float* __restrict__ Whh, const float* __restrict__ bhh,
                       unsigned* ctl, unsigned* hr1, unsigned* hr2,
                       float* xgr, float* __restrict__ out, int s, char* smem) {
  short*    hstage = (short*)smem;                         // [2][16][528]  33792B
  float*    stash  = (float*)(smem + 33792);               // [2][256][24]  49152B
  unsigned* ylds   = (unsigned*)(smem + 33792 + 49152);    // [2][256][8]   16384B
  float*    gb     = (float*)(smem + 99328);               // [16][400]     25600B
  float*    bhl    = (float*)(smem + 124928);              // [384]          1536B

  const int tid = threadIdx.x;
  const int w = tid >> 6, lane = tid & 63, c = lane & 15, q = lane >> 4;
  const int b = tid >> 4, kc = tid & 15;      // staging + epilogue batch
  const int u0 = kc * 8;                      // epilogue unit base (local)

  unsigned* ownring = LAYER ? hr2 : hr1;
  unsigned* recprog = ctl + LAYER * 4;
  unsigned* xgtag   = ctl + 64 + LAYER * (NSLOT * 8);
  unsigned* recprog2 = ctl + 4;
  unsigned* xgtag2   = ctl + 64 + (NSLOT * 8);

  for (int i = tid; i < 384; i += 256) {
    const int g = i >> 7, u = i & 127;
    bhl[i] = bhh[g * HD + s * 128 + u];
  }
  // stationary W_hh: wave w -> local rows [w*96, w*96+96) (6 N-tiles)
  bf16x8 wf[6][16];
  #pragma unroll
  for (int nt = 0; nt < 6; ++nt) {
    const int lr = w * 96 + nt * 16 + c;
    const int g = lr >> 7, u = lr & 127;
    const float* pw = Whh + ((size_t)(g * HD + s * 128 + u)) * HD + q * 8;
    #pragma unroll
    for (int kk = 0; kk < 16; ++kk) {
      bf16x8 f;
      #pragma unroll
      for (int i = 0; i < 8; ++i) f[i] = (short)f2bf(pw[kk * 32 + i]);
      wf[nt][kk] = f;
    }
  }
  __syncthreads();

  f32x4 h0 = {0.f,0.f,0.f,0.f}, h1 = {0.f,0.f,0.f,0.f};  // own h fp32 (b,u0..u0+7)
  int haveXG = 0, haveY = 0;

  for (int t = 0; t < SEQ; ++t) {
    const int buf = t & 1, slot = t & (NSLOT - 1);
    // ------------- phase A -------------
    {
      if (LAYER == 0 && tid == 0 && t >= 32 && (t & 7) == 0) {
        // y-ring reuse: need L2 helpers + L2 rec past step t-24
        const unsigned need = (unsigned)(t - 23);
        const int ck = (t - 24) & (NSLOT - 1);
        for (;;) {
          u32x4 ta, tb, pr;
          ld_u32x4_nw(&ta, xgtag2 + ck * 8);
          ld_u32x4_nw(&tb, xgtag2 + ck * 8 + 4);
          ld_u32x4_nw(&pr, recprog2);
          vmwait0();
          bool ok = true;
          #pragma unroll
          for (int e = 0; e < 4; ++e)
            ok = ok && ta[e] >= need && tb[e] >= need && pr[e] >= need;
          if (ok) break;
          __builtin_amdgcn_s_sleep(32);
        }
      }
      // issue h loads + xgtag(t+1) + y(t+1) together
      u32x4 hv[8];
      const unsigned htag = (unsigned)t;
      const unsigned* hp = ownring + (size_t)((t - 1) & (NSLOT - 1)) * SLOTU + b * HD + kc * 32;
      if (t > 0) {
        #pragma unroll
        for (int g2 = 0; g2 < 8; ++g2) ld_u32x4_nw(&hv[g2], hp + g2 * 4);
      }
      u32x4 tga = {0,0,0,0}, tgb = {0,0,0,0}, yv0 = {0,0,0,0}, yv1 = {0,0,0,0};
      const int nslot = (t + 1) & (NSLOT - 1);
      if (t + 1 < SEQ) {
        ld_u32x4_nw(&tga, xgtag + nslot * 8);
        ld_u32x4_nw(&tgb, xgtag + nslot * 8 + 4);
        if (LAYER == 1) {
          const unsigned* yp = hr1 + (size_t)nslot * SLOTU + b * HD + s * 128 + u0;
          ld_u32x4_nw(&yv0, yp);
          ld_u32x4_nw(&yv1, yp + 4);
        }
      }
      vmwait0();
      // h verify: direct full re-poll (8 granules)
      if (t > 0) {
        for (;;) {
          unsigned bad = 0;
          #pragma unroll
          for (int g2 = 0; g2 < 8; ++g2)
            #pragma unroll
            for (int e = 0; e < 4; ++e) bad |= hv[g2][e] ^ htag;
          if (!(bad & 0xffffu)) break;
          __builtin_amdgcn_s_sleep(1);
          #pragma unroll
          for (int g2 = 0; g2 < 8; ++g2) ld_u32x4_nw(&hv[g2], hp + g2 * 4);
          vmwait0();
        }
        stage_lds(hv, hstage + buf * (16 * ROWS), b, kc);
      }
      // xg(t) fallback if not prefetched
      if (!haveXG) {
        const unsigned need = (unsigned)(t + 1);
        for (;;) {
          u32x4 ta, tb;
          ld_u32x4_nw(&ta, xgtag + slot * 8);
          ld_u32x4_nw(&tb, xgtag + slot * 8 + 4);
          vmwait0();
          bool ok = true;
          #pragma unroll
          for (int e = 0; e < 4; ++e) ok = ok && ta[e] == need && tb[e] == need;
          if (ok) break;
          __builtin_amdgcn_s_sleep(4);
        }
        f32x4 xv[6];
        const float* xp = xgr + ((size_t)slot * 16 + b) * XROW + s * 128 + u0;
        #pragma unroll
        for (int g2 = 0; g2 < 3; ++g2) {
          ld_f32x4_sc(&xv[g2 * 2],     xp + g2 * HD);
          ld_f32x4_sc(&xv[g2 * 2 + 1], xp + g2 * HD + 4);
        }
        vmwait0();
        float* st = stash + (buf * 256 + tid) * 24;
        #pragma unroll
        for (int g2 = 0; g2 < 6; ++g2) *(f32x4*)(st + g2 * 4) = xv[g2];
      }
      // y(t) fallback (L2)
      if (LAYER == 1 && !haveY) {
        const unsigned need = (unsigned)(t + 1);
        const unsigned* yp = hr1 + (size_t)slot * SLOTU + b * HD + s * 128 + u0;
        u32x4 a0, a1;
        for (;;) {
          ld_u32x4_nw(&a0, yp);
          ld_u32x4_nw(&a1, yp + 4);
          vmwait0();
          unsigned bad = 0;
          #pragma unroll
          for (int e = 0; e < 4; ++e) bad |= (a0[e] ^ need) | (a1[e] ^ need);
          if (!(bad & 0xffffu)) break;
          __builtin_amdgcn_s_sleep(2);
        }
        unsigned* yd = ylds + (buf * 256 + tid) * 8;
        *(u32x4*)yd = a0;
        *(u32x4*)(yd + 4) = a1;
      }
      // prefetch xg(t+1) / y(t+1) if tags fresh
      haveXG = 0; haveY = 0;
      if (t + 1 < SEQ) {
        const unsigned need = (unsigned)(t + 2);
        bool okx = true;
        #pragma unroll
        for (int e = 0; e < 4; ++e) okx = okx && tga[e] == need && tgb[e] == need;
        if (okx) {
          f32x4 xv[6];
          const float* xp = xgr + ((size_t)nslot * 16 + b) * XROW + s * 128 + u0;
          #pragma unroll
          for (int g2 = 0; g2 < 3; ++g2) {
            ld_f32x4_sc(&xv[g2 * 2],     xp + g2 * HD);
            ld_f32x4_sc(&xv[g2 * 2 + 1], xp + g2 * HD + 4);
          }
          vmwait0();
          float* st = stash + ((buf ^ 1) * 256 + tid) * 24;
          #pragma unroll
          for (int g2 = 0; g2 < 6; ++g2) *(f32x4*)(st + g2 * 4) = xv[g2];
          haveXG = 1;
        }
        if (LAYER == 1) {
          unsigned bad = 0;
          #pragma unroll
          for (int e = 0; e < 4; ++e) bad |= (yv0[e] ^ need) | (yv1[e] ^ need);
          if (!(bad & 0xffffu)) {
            unsigned* yd = ylds + ((buf ^ 1) * 256 + tid) * 8;
            *(u32x4*)yd = yv0;
            *(u32x4*)(yd + 4) = yv1;
            haveY = 1;
          }
        }
      }
    }
    __syncthreads();  // B1
    if (tid == 255) st_u32_sc(&recprog[s], (unsigned)(t + 1));

    // ------------- matvec: 96 MFMA/wave -------------
    {
      f32x4 acc[6] = {{0.f,0.f,0.f,0.f},{0.f,0.f,0.f,0.f},{0.f,0.f,0.f,0.f},
                      {0.f,0.f,0.f,0.f},{0.f,0.f,0.f,0.f},{0.f,0.f,0.f,0.f}};
      if (t > 0) {
        const short* ap = hstage + buf * (16 * ROWS) + c * ROWS + q * 8;
        #pragma unroll
        for (int kk = 0; kk < 16; ++kk) {
          bf16x8 a = *(const bf16x8*)(ap + kk * 32);
          #pragma unroll
          for (int nt = 0; nt < 6; ++nt) acc[nt] = MFMA16(a, wf[nt][kk], acc[nt]);
        }
      }
      #pragma unroll
      for (int nt = 0; nt < 6; ++nt) {
        const int lr = w * 96 + nt * 16 + c;
        #pragma unroll
        for (int j = 0; j < 4; ++j) gb[(q * 4 + j) * 400 + lr] = acc[nt][j];
      }
    }
    __syncthreads();  // B2

    // ------------- epilogue -------------
    {
      const float* st = stash + (buf * 256 + tid) * 24;
      u32x4 pk0, pk1;
      float hv8[8];
      #pragma unroll
      for (int i = 0; i < 8; ++i) {
        const int u = u0 + i;
        const float xr_ = st[i], xz_ = st[8 + i], xn_ = st[16 + i];
        const float hr_ = gb[b * 400 + u] + bhl[u];
        const float hz_ = gb[b * 400 + 128 + u] + bhl[128 + u];
        const float hn_ = gb[b * 400 + 256 + u] + bhl[256 + u];
        const float r = sigm(xr_ + hr_);
        const float z = sigm(xz_ + hz_);
        const float nn = tanh_(xn_ + r * hn_);
        const float hp = (i < 4) ? h0[i & 3] : h1[i & 3];
        const float hv = (1.f - z) * nn + z * hp;
        if (i < 4) h0[i & 3] = hv; else h1[i & 3] = hv;
        hv8[i] = hv;
        const unsigned pw = ((unsigned)f2bf(hv) << 16) | (unsigned)(t + 1);
        if (i < 4) pk0[i & 3] = pw; else pk1[i & 3] = pw;
      }
      unsigned* op = ownring + (size_t)slot * SLOTU + b * HD + s * 128 + u0;
      st_u32x4_sc(op, pk0);
      st_u32x4_sc(op + 4, pk1);
      if (LAYER == 1) {
        const unsigned* yd = ylds + (buf * 256 + tid) * 8;
        f32x4 o0, o1;
        #pragma unroll
        for (int i = 0; i < 4; ++i) {
          o0[i] = hv8[i] + bf2f((unsigned short)(yd[i] >> 16));
          o1[i] = hv8[4 + i] + bf2f((unsigned short)(yd[4 + i] >> 16));
        }
        float* po = out + ((size_t)b * SEQ + t) * HD + s * 128 + u0;
        *(f32x4*)po = o0;
        *(f32x4*)(po + 4) = o1;
      }
    }
  }
}

// ---------------- helper WG: xg producer, 192 rows ----------------
template <int LAYER>
__device__ void helper_fn(const float* __restrict__ x,
                          const float* __restrict__ Wih, const float* __restrict__ bih,
                          unsigned* ctl, unsigned* hr1, float* xgr, int h, char* smem) {
  short* astage = (short*)smem;   // [16][528]
  const int tid = threadIdx.x;
  const int w = tid >> 6, lane = tid & 63, c = lane & 15, q = lane >> 4;
  const int b = tid >> 4, kc = tid & 15;
  unsigned* recprog = ctl + LAYER * 4;
  unsigned* xgtag   = ctl + 64 + LAYER * (NSLOT * 8);

  bf16x8 wfh[3][16];
  float bias[3];
  #pragma unroll
  for (int ti = 0; ti < 3; ++ti) {
    const int grow = h * 192 + w * 48 + ti * 16 + c;
    bias[ti] = bih[grow];
    const float* pw = Wih + (size_t)grow * HD + q * 8;
    #pragma unroll
    for (int kk = 0; kk < 16; ++kk) {
      bf16x8 f;
      #pragma unroll
      for (int i = 0; i < 8; ++i) f[i] = (short)f2bf(pw[kk * 32 + i]);
      wfh[ti][kk] = f;
    }
  }

  for (int t = 0; t < SEQ; ++t) {
    const int slot = t & (NSLOT - 1);
    if (tid == 0 && t >= NSLOT && (t & 7) == 0) {
      const unsigned need = (unsigned)(t - 16);
      for (;;) {
        u32x4 pr;
        ld_u32x4_nw(&pr, recprog);
        vmwait0();
        if (pr[0] >= need && pr[1] >= need && pr[2] >= need && pr[3] >= need) break;
        __builtin_amdgcn_s_sleep(32);
      }
    }
    if (LAYER == 0) {
      f32x4 xl[8];
      const float* px = x + ((size_t)b * SEQ + t) * HD + kc * 32;
      #pragma unroll
      for (int g2 = 0; g2 < 8; ++g2) xl[g2] = *(const f32x4*)(px + g2 * 4);
      stage_x(xl, astage, b, kc);
    } else {
      // poll y_t chunk (tag-in-data)
      u32x4 v0[8];
      const unsigned* yp = hr1 + (size_t)slot * SLOTU + b * HD + kc * 32;
      const unsigned need = (unsigned)(t + 1);
      #pragma unroll
      for (int g2 = 0; g2 < 8; ++g2) ld_u32x4_nw(&v0[g2], yp + g2 * 4);
      vmwait0();
      for (;;) {
        unsigned bad = 0;
        #pragma unroll
        for (int g2 = 0; g2 < 8; ++g2)
          #pragma unroll
          for (int e = 0; e < 4; ++e) bad |= v0[g2][e] ^ need;
        if (!(bad & 0xffffu)) break;
        __builtin_amdgcn_s_sleep(1);
        #pragma unroll
        for (int g2 = 0; g2 < 8; ++g2) ld_u32x4_nw(&v0[g2], yp + g2 * 4);
        vmwait0();
      }
      stage_lds(v0, astage, b, kc);
    }
    __syncthreads();  // stage ready

    f32x4 acc[3] = {{0.f,0.f,0.f,0.f},{0.f,0.f,0.f,0.f},{0.f,0.f,0.f,0.f}};
    const short* ap = astage + c * ROWS + q * 8;
    #pragma unroll
    for (int kk = 0; kk < 16; ++kk) {
      bf16x8 a = *(const bf16x8*)(ap + kk * 32);
      #pragma unroll
      for (int ti = 0; ti < 3; ++ti) acc[ti] = MFMA16(a, wfh[ti][kk], acc[ti]);
    }
    #pragma unroll
    for (int ti = 0; ti < 3; ++ti) {
      const int grow = h * 192 + w * 48 + ti * 16 + c;
      #pragma unroll
      for (int j = 0; j < 4; ++j)
        st_f32_sc(xgr + ((size_t)slot * 16 + (q * 4 + j)) * XROW + grow,
                  acc[ti][j] + bias[ti]);
    }
    vmwait0();
    __syncthreads();  // all stores acked
    if (tid == 0) st_u32_sc(&xgtag[slot * 8 + h], (unsigned)(t + 1));
  }
}

__global__ __launch_bounds__(256, 1) void gru2_k(
    const float* __restrict__ x,
    const float* __restrict__ Wih1, const float* __restrict__ Whh1,
    const float* __restrict__ bih1, const float* __restrict__ bhh1,
    const float* __restrict__ Wih2, const float* __restrict__ Whh2,
    const float* __restrict__ bih2, const float* __restrict__ bhh2,
    float* __restrict__ out,
    unsigned* ctl, unsigned* hr1, unsigned* hr2, float* xg1, float* xg2) {
  __shared__ alignas(16) char smem[126464];
  const int bx = blockIdx.x;
  if (bx < 4)
    rec_fn<0>(Whh1, bhh1, ctl, hr1, hr2, xg1, out, bx, smem);
  else if (bx < 8)
    rec_fn<1>(Whh2, bhh2, ctl, hr1, hr2, xg2, out, bx - 4, smem);
  else if (bx < 16)
    helper_fn<0>(x, Wih1, bih1, ctl, hr1, xg1, bx - 8, smem);
  else
    helper_fn<1>(x, Wih2, bih2, ctl, hr1, xg2, bx - 16, smem);
}

}  // namespace

extern "C" void kernel_launch(void* const* d_in, const int* in_sizes, int n_in,
                              void* d_out, int out_size, void* d_ws, size_t ws_size,
                              hipStream_t stream) {
  const float* x    = (const float*)d_in[0];
  const float* Wih1 = (const float*)d_in[1];
  const float* Whh1 = (const float*)d_in[2];
  const float* bih1 = (const float*)d_in[3];
  const float* bhh1 = (const float*)d_in[4];
  const float* Wih2 = (const float*)d_in[5];
  const float* Whh2 = (const float*)d_in[6];
  const float* bih2 = (const float*)d_in[7];
  const float* bhh2 = (const float*)d_in[8];

  unsigned* ctl = (unsigned*)d_ws;                                  // 4 KB (memset)
  unsigned* hr1 = (unsigned*)((char*)d_ws + 4096);                  // 1 MB
  unsigned* hr2 = hr1 + (size_t)NSLOT * SLOTU;                      // 1 MB
  float* xg1 = (float*)((char*)d_ws + 4096 + 2 * NSLOT * SLOTU * 4); // 3 MB
  float* xg2 = xg1 + (size_t)NSLOT * 16 * XROW;                      // 3 MB

  // progress words + xg tags must be zero at every launch
  hipMemsetAsync(d_ws, 0, 4096, stream);

  gru2_k<<<dim3(24), dim3(256), 0, stream>>>(
      x, Wih1, Whh1, bih1, bhh1, Wih2, Whh2, bih2, bhh2,
      (float*)d_out, ctl, hr1, hr2, xg1, xg2);
}